// Round 3
// baseline (11864.347 us; speedup 1.0000x reference)
//
#include <hip/hip_runtime.h>
#include <stdint.h>

#define SEQ    512
#define NBATCH 64
#define HID    1024
#define GDIM   4096

typedef __attribute__((ext_vector_type(4))) float          f32x4;
typedef __attribute__((ext_vector_type(8))) short          s16x8;
typedef __attribute__((ext_vector_type(4))) unsigned short u16x4;

#define MFMA_BF16(a,b,c) __builtin_amdgcn_mfma_f32_16x16x32_bf16((a),(b),(c),0,0,0)

__device__ __forceinline__ unsigned short f2bf(float f){
  union { float f; unsigned u; } v; v.f = f;
  unsigned r = v.u + 0x7fffu + ((v.u >> 16) & 1u);
  return (unsigned short)(r >> 16);
}

__device__ __forceinline__ void gload_lds16(const void* g, void* l){
  __builtin_amdgcn_global_load_lds((const __attribute__((address_space(1))) void*)g,
                                   (__attribute__((address_space(3))) void*)l,
                                   16, 0, 0);
}

// ---------------- fp32 -> bf16 bulk convert (n4 = elements/4) ----------------
__global__ __launch_bounds__(256) void cvt_bf16(const float* __restrict__ s,
                                                unsigned short* __restrict__ d, int n4){
  int i = blockIdx.x*256 + threadIdx.x;
  if (i >= n4) return;
  f32x4 v = *(const f32x4*)(s + (size_t)i*4);
  u16x4 o;
  o[0]=f2bf(v[0]); o[1]=f2bf(v[1]); o[2]=f2bf(v[2]); o[3]=f2bf(v[3]);
  *(u16x4*)(d + (size_t)i*4) = o;
}

// ---------------- init: h0 -> hbuf[0] (bf16), c0 -> cstate ----------------
__global__ __launch_bounds__(256) void init_state(const float* __restrict__ h0,
                                                  const float* __restrict__ c0,
                                                  unsigned short* __restrict__ hbuf,
                                                  float* __restrict__ cstate){
  int i = blockIdx.x*256 + threadIdx.x;   // 65536 total
  hbuf[i]   = f2bf(h0[i]);
  cstate[i] = c0[i];
}

// ---------------- x_proj GEMM: C[M][4096] = A[M][1024] * Bw[4096][1024]^T + bias ----
__global__ __launch_bounds__(256,1) void gemm_xproj(
    const unsigned short* __restrict__ A,   // bf16 [M][1024]
    const unsigned short* __restrict__ Bw,  // bf16 [4096][1024]
    const float* __restrict__ bih, const float* __restrict__ bhh,
    float* __restrict__ C, int M)
{
  __shared__ unsigned short Al[2][128*64];
  __shared__ unsigned short Bl[2][128*64];

  const int bm = blockIdx.x >> 5;
  const int bn = blockIdx.x & 31;
  const int tid = threadIdx.x;
  const int wv = tid >> 6, l = tid & 63;
  const int wm = wv >> 1, wn = wv & 1;
  const int c16 = l & 15, rq = l >> 4;

  const unsigned short* Ab = A  + (size_t)bm*128*1024;
  const unsigned short* Bb = Bw + (size_t)bn*128*1024;

  f32x4 acc[4][4];
#pragma unroll
  for (int i=0;i<4;++i)
#pragma unroll
    for (int j=0;j<4;++j) acc[i][j] = (f32x4){0.f,0.f,0.f,0.f};

  auto stage = [&](int buf, int kt){
    const int k0 = kt*64;
    const int rsub = wv*8 + (l>>3);
    const int col  = (l&7)*8;
#pragma unroll
    for (int is=0; is<4; ++is){
      const int row = is*32 + rsub;
      gload_lds16(Ab + (size_t)row*1024 + k0 + col, &Al[buf][row*64 + col]);
      gload_lds16(Bb + (size_t)row*1024 + k0 + col, &Bl[buf][row*64 + col]);
    }
  };

  stage(0, 0);
  asm volatile("s_waitcnt vmcnt(0)" ::: "memory");
  __syncthreads();

  for (int kt = 0; kt < 16; ++kt){
    const int cur = kt & 1;
    if (kt < 15) stage(cur^1, kt+1);
#pragma unroll
    for (int ks=0; ks<2; ++ks){
      s16x8 afr[4], bfr[4];
#pragma unroll
      for (int mi=0;mi<4;++mi)
        afr[mi] = *(const s16x8*)&Al[cur][(wm*64 + mi*16 + c16)*64 + ks*32 + rq*8];
#pragma unroll
      for (int ni=0;ni<4;++ni)
        bfr[ni] = *(const s16x8*)&Bl[cur][(wn*64 + ni*16 + c16)*64 + ks*32 + rq*8];
#pragma unroll
      for (int mi=0;mi<4;++mi)
#pragma unroll
        for (int ni=0;ni<4;++ni)
          acc[mi][ni] = MFMA_BF16(afr[mi], bfr[ni], acc[mi][ni]);
    }
    asm volatile("s_waitcnt vmcnt(0)" ::: "memory");
    __syncthreads();
  }

  const int crow0 = bm*128 + wm*64;
  const int ccol0 = bn*128 + wn*64;
#pragma unroll
  for (int ni=0;ni<4;++ni){
    const int col = ccol0 + ni*16 + c16;
    const float bsum = bih[col] + bhh[col];
#pragma unroll
    for (int mi=0;mi<4;++mi){
      const int row = crow0 + mi*16 + rq*4;
#pragma unroll
      for (int r=0;r<4;++r)
        C[(size_t)(row+r)*GDIM + col] = acc[mi][ni][r] + bsum;
    }
  }
}

// ---------------- persistent recurrence over one chunk of timesteps ----------------
// 256 blocks x 512 threads. Block b owns hidden cols [4b, 4b+4) -> 16 gate rows.
// Release: h + flags write-through to LLC (sc0 sc1) + vmcnt(0). Acquire: poll
// flags at LLC (sc0 sc1), then agent-acquire fence (buffer_inv) so the h
// broadcast is served by the per-XCD L2 (32 blocks share one 128KB fetch).
__global__ __launch_bounds__(512,2) void lstm_rec(
    const unsigned short* __restrict__ whhb,   // bf16 [4096][1024]
    const float* __restrict__ xproj,           // fp32 [nsteps*64][4096]
    unsigned short* __restrict__ hbuf,         // bf16 [3][64*1024] ring
    float* __restrict__ cstate,                // fp32 [64*1024]
    float* __restrict__ outp,                  // fp32 d_out base
    unsigned int* __restrict__ bar,            // 256 flags, stride 32 uints
    int t0, int nsteps)
{
  const int tid = threadIdx.x;
  const int wv = tid >> 6, l = tid & 63;
  const int mt = wv >> 1, kh = wv & 1;       // batch tile 0..3, K half 0..1
  const int c16 = l & 15, rq = l >> 4;
  const int hc0 = blockIdx.x * 4;
  const int eb = tid >> 2, ej = tid & 3;     // epilogue (batch, hidden col), tid<256

  __shared__ float part[8*16*17];            // [wave][b_local][gate row pad17]
  __shared__ unsigned short hsh[64*4];       // h bf16 staging for coalesced store

  // ---- W_hh slice (16 gate rows) -> registers; gate row nl=c16, j=nl>>2, g=nl&3
  s16x8 breg[16];
#pragma unroll
  for (int ks = 0; ks < 16; ++ks){
    const int j = c16 >> 2, g = c16 & 3;
    const int grow = g*HID + hc0 + j;
    const int k = kh*512 + ks*32 + rq*8;
    breg[ks] = *(const s16x8*)(whhb + (size_t)grow*HID + k);
  }

  float creg = 0.f;
  float xp0=0.f, xp1=0.f, xp2=0.f, xp3=0.f;
  if (tid < 256){
    creg = cstate[(size_t)eb*HID + hc0 + ej];
    xp0 = xproj[(size_t)eb*GDIM + 0*HID + hc0 + ej];
    xp1 = xproj[(size_t)eb*GDIM + 1*HID + hc0 + ej];
    xp2 = xproj[(size_t)eb*GDIM + 2*HID + hc0 + ej];
    xp3 = xproj[(size_t)eb*GDIM + 3*HID + hc0 + ej];
  }

  int rb = t0 % 3;
  for (int t = t0; t < t0 + nsteps; ++t){
    int wb = rb + 1; if (wb == 3) wb = 0;

    // ---- h fragments: plain cached loads (L2-shared across 32 blocks/XCD)
    const unsigned short* hrow = hbuf + (size_t)rb*65536
                               + (size_t)(mt*16 + c16)*HID + kh*512 + rq*8;
    s16x8 af[16];
#pragma unroll
    for (int ks = 0; ks < 16; ++ks)
      af[ks] = *(const s16x8*)(hrow + ks*32);

    f32x4 acc = (f32x4){0.f,0.f,0.f,0.f};
#pragma unroll
    for (int ks = 0; ks < 16; ++ks)
      acc = MFMA_BF16(af[ks], breg[ks], acc);

    // ---- partials -> LDS
#pragma unroll
    for (int r = 0; r < 4; ++r)
      part[(wv*16 + rq*4 + r)*17 + c16] = acc[r];
    __syncthreads();

    // ---- epilogue (256 threads): sum K halves, activations, state update
    if (tid < 256){
      const int mt_e = eb >> 4, bl_e = eb & 15;
      const int b0 = ((mt_e*2 + 0)*16 + bl_e)*17;
      const int b1 = ((mt_e*2 + 1)*16 + bl_e)*17;
      const float vi = part[b0 + ej*4 + 0] + part[b1 + ej*4 + 0] + xp0;
      const float vf = part[b0 + ej*4 + 1] + part[b1 + ej*4 + 1] + xp1;
      const float vg = part[b0 + ej*4 + 2] + part[b1 + ej*4 + 2] + xp2;
      const float vo = part[b0 + ej*4 + 3] + part[b1 + ej*4 + 3] + xp3;

      const float ig = 1.f/(1.f + __expf(-vi));
      const float fg = 1.f/(1.f + __expf(-vf));
      const float gg = tanhf(vg);
      const float og = 1.f/(1.f + __expf(-vo));
      creg = fg*creg + ig*gg;
      const float h = og * tanhf(creg);

      const size_t oidx = (size_t)eb*HID + hc0 + ej;
      outp[(size_t)t*65536 + oidx] = h;
      hsh[eb*4 + ej] = f2bf(h);
      if (t == SEQ-1){
        outp[(size_t)SEQ*65536 + oidx]         = h;     // h_last
        outp[(size_t)SEQ*65536 + 65536 + oidx] = creg;  // c_last
      }
      // prefetch next step's xproj before the barrier (hidden under poll)
      if (t+1 < t0 + nsteps){
        const size_t xrow = (size_t)(t+1 - t0)*NBATCH + eb;
        xp0 = xproj[xrow*GDIM + 0*HID + hc0 + ej];
        xp1 = xproj[xrow*GDIM + 1*HID + hc0 + ej];
        xp2 = xproj[xrow*GDIM + 2*HID + hc0 + ej];
        xp3 = xproj[xrow*GDIM + 3*HID + hc0 + ej];
      }
    }
    __syncthreads();                         // hsh visible

    // ---- coalesced h ring store: 64 threads x 8B, write-through to LLC
    if (tid < 64){
      const unsigned short* hp = hbuf + (size_t)wb*65536 + (size_t)tid*HID + hc0;
      unsigned long long hv = *(const unsigned long long*)&hsh[tid*4];
      asm volatile("global_store_dwordx2 %0, %1, off sc0 sc1"
                   :: "v"(hp), "v"(hv) : "memory");
    }

    // ---- release: drain (acks = data at LLC), then flag
    asm volatile("s_waitcnt vmcnt(0)" ::: "memory");
    __syncthreads();
    if (tid == 0){
      unsigned int* fp = bar + (blockIdx.x << 5);
      unsigned int fv = (unsigned int)(t + 1);
      asm volatile("global_store_dword %0, %1, off sc0 sc1"
                   :: "v"(fp), "v"(fv) : "memory");
    }
    // ---- acquire: 256 threads poll 256 flags in parallel (LLC loads)
    if (tid < 256){
      const unsigned int* fq = bar + (tid << 5);
      unsigned int fv; int spins = 0;
      do {
        asm volatile("global_load_dword %0, %1, off sc0 sc1\n\ts_waitcnt vmcnt(0)"
                     : "=v"(fv) : "v"(fq) : "memory");
      } while (fv < (unsigned int)(t + 1) && ++spins < (1 << 17));
    }
    __syncthreads();
    // invalidate stale L1/L2 lines so next step's h loads hit fresh data
    __builtin_amdgcn_fence(__ATOMIC_ACQUIRE, "agent");

    rb = wb;
  }

  if (tid < 256) cstate[(size_t)eb*HID + hc0 + ej] = creg;
}

// ---------------------------------------------------------------------------
extern "C" void kernel_launch(void* const* d_in, const int* in_sizes, int n_in,
                              void* d_out, int out_size, void* d_ws, size_t ws_size,
                              hipStream_t stream)
{
  const float* inp = (const float*)d_in[0];
  const float* wih = (const float*)d_in[1];
  const float* whh = (const float*)d_in[2];
  const float* bih = (const float*)d_in[3];
  const float* bhh = (const float*)d_in[4];
  const float* h0  = (const float*)d_in[5];
  const float* c0  = (const float*)d_in[6];
  float* outp = (float*)d_out;

  auto alignup = [](size_t x){ return (x + 255) & ~(size_t)255; };
  auto need = [&](size_t ch)->size_t{
    size_t s = 0;
    s += alignup(ch*64*4096*4);          // xproj chunk
    s += alignup(ch*64*1024*2);          // in_bf16 chunk
    s += alignup((size_t)4096*1024*2);   // wih_bf16
    s += alignup((size_t)4096*1024*2);   // whh_bf16
    s += alignup((size_t)3*64*1024*2);   // hbuf ring
    s += alignup((size_t)64*1024*4);     // cstate
    s += alignup((size_t)256*32*4);      // flags
    return s;
  };
  int CH = 512;
  while (CH > 2 && need(CH) > ws_size) CH >>= 1;

  char* w = (char*)d_ws;
  float*          xproj  = (float*)w;          w += alignup((size_t)CH*64*4096*4);
  unsigned short* in_bf  = (unsigned short*)w; w += alignup((size_t)CH*64*1024*2);
  unsigned short* wih_bf = (unsigned short*)w; w += alignup((size_t)4096*1024*2);
  unsigned short* whh_bf = (unsigned short*)w; w += alignup((size_t)4096*1024*2);
  unsigned short* hbuf   = (unsigned short*)w; w += alignup((size_t)3*64*1024*2);
  float*          cst    = (float*)w;          w += alignup((size_t)64*1024*4);
  unsigned int*   bar    = (unsigned int*)w;

  hipMemsetAsync(bar, 0, 256*32*4, stream);

  cvt_bf16<<<4096, 256, 0, stream>>>(wih, wih_bf, 4096*1024/4);
  cvt_bf16<<<4096, 256, 0, stream>>>(whh, whh_bf, 4096*1024/4);
  init_state<<<256, 256, 0, stream>>>(h0, c0, hbuf, cst);

  const int nch = SEQ / CH;
  for (int ci = 0; ci < nch; ++ci){
    const int t0 = ci * CH;
    const int n4 = CH*64*1024/4;
    cvt_bf16<<<(n4+255)/256, 256, 0, stream>>>(inp + (size_t)t0*65536, in_bf, n4);
    gemm_xproj<<<dim3((CH*64/128)*32), 256, 0, stream>>>(in_bf, wih_bf, bih, bhh,
                                                         xproj, CH*64);
    lstm_rec<<<dim3(256), dim3(512), 0, stream>>>(whh_bf, xproj, hbuf, cst, outp,
                                                  bar, t0, CH);
  }
}

// Round 4
// 3662.210 us; speedup vs baseline: 3.2397x; 3.2397x over previous
//
#include <hip/hip_runtime.h>
#include <stdint.h>

#define SEQ    512
#define NBATCH 64
#define HID    1024
#define GDIM   4096

typedef __attribute__((ext_vector_type(4))) float          f32x4;
typedef __attribute__((ext_vector_type(8))) short          s16x8;
typedef __attribute__((ext_vector_type(4))) unsigned short u16x4;

#define MFMA_BF16(a,b,c) __builtin_amdgcn_mfma_f32_16x16x32_bf16((a),(b),(c),0,0,0)

__device__ __forceinline__ unsigned short f2bf(float f){
  union { float f; unsigned u; } v; v.f = f;
  unsigned r = v.u + 0x7fffu + ((v.u >> 16) & 1u);
  return (unsigned short)(r >> 16);
}

__device__ __forceinline__ void gload_lds16(const void* g, void* l){
  __builtin_amdgcn_global_load_lds((const __attribute__((address_space(1))) void*)g,
                                   (__attribute__((address_space(3))) void*)l,
                                   16, 0, 0);
}

// ---------------- fp32 -> bf16 bulk convert (n4 = elements/4) ----------------
__global__ __launch_bounds__(256) void cvt_bf16(const float* __restrict__ s,
                                                unsigned short* __restrict__ d, int n4){
  int i = blockIdx.x*256 + threadIdx.x;
  if (i >= n4) return;
  f32x4 v = *(const f32x4*)(s + (size_t)i*4);
  u16x4 o;
  o[0]=f2bf(v[0]); o[1]=f2bf(v[1]); o[2]=f2bf(v[2]); o[3]=f2bf(v[3]);
  *(u16x4*)(d + (size_t)i*4) = o;
}

// ---------------- init: h0 -> hbuf[0] (bf16, SWIZZLED layout), c0 -> cstate ----
// hbuf row layout: byte = b*2048 + ((chunk ^ (b&7))<<4) + (k&7)*2, chunk = k>>3
__global__ __launch_bounds__(256) void init_state(const float* __restrict__ h0,
                                                  const float* __restrict__ c0,
                                                  unsigned short* __restrict__ hbuf,
                                                  float* __restrict__ cstate){
  int i = blockIdx.x*256 + threadIdx.x;   // 65536 total
  int b = i >> 10, c = i & 1023;
  int sw = (c >> 3) ^ (b & 7);
  hbuf[b*1024 + sw*8 + (c & 7)] = f2bf(h0[i]);
  cstate[i] = c0[i];
}

// ---------------- x_proj GEMM: C[M][4096] = A[M][1024] * Bw[4096][1024]^T + bias ----
__global__ __launch_bounds__(256,1) void gemm_xproj(
    const unsigned short* __restrict__ A,   // bf16 [M][1024]
    const unsigned short* __restrict__ Bw,  // bf16 [4096][1024]
    const float* __restrict__ bih, const float* __restrict__ bhh,
    float* __restrict__ C, int M)
{
  __shared__ unsigned short Al[2][128*64];
  __shared__ unsigned short Bl[2][128*64];

  const int bm = blockIdx.x >> 5;
  const int bn = blockIdx.x & 31;
  const int tid = threadIdx.x;
  const int wv = tid >> 6, l = tid & 63;
  const int wm = wv >> 1, wn = wv & 1;
  const int c16 = l & 15, rq = l >> 4;

  const unsigned short* Ab = A  + (size_t)bm*128*1024;
  const unsigned short* Bb = Bw + (size_t)bn*128*1024;

  f32x4 acc[4][4];
#pragma unroll
  for (int i=0;i<4;++i)
#pragma unroll
    for (int j=0;j<4;++j) acc[i][j] = (f32x4){0.f,0.f,0.f,0.f};

  auto stage = [&](int buf, int kt){
    const int k0 = kt*64;
    const int rsub = wv*8 + (l>>3);
    const int col  = (l&7)*8;
#pragma unroll
    for (int is=0; is<4; ++is){
      const int row = is*32 + rsub;
      gload_lds16(Ab + (size_t)row*1024 + k0 + col, &Al[buf][row*64 + col]);
      gload_lds16(Bb + (size_t)row*1024 + k0 + col, &Bl[buf][row*64 + col]);
    }
  };

  stage(0, 0);
  asm volatile("s_waitcnt vmcnt(0)" ::: "memory");
  __syncthreads();

  for (int kt = 0; kt < 16; ++kt){
    const int cur = kt & 1;
    if (kt < 15) stage(cur^1, kt+1);
#pragma unroll
    for (int ks=0; ks<2; ++ks){
      s16x8 afr[4], bfr[4];
#pragma unroll
      for (int mi=0;mi<4;++mi)
        afr[mi] = *(const s16x8*)&Al[cur][(wm*64 + mi*16 + c16)*64 + ks*32 + rq*8];
#pragma unroll
      for (int ni=0;ni<4;++ni)
        bfr[ni] = *(const s16x8*)&Bl[cur][(wn*64 + ni*16 + c16)*64 + ks*32 + rq*8];
#pragma unroll
      for (int mi=0;mi<4;++mi)
#pragma unroll
        for (int ni=0;ni<4;++ni)
          acc[mi][ni] = MFMA_BF16(afr[mi], bfr[ni], acc[mi][ni]);
    }
    asm volatile("s_waitcnt vmcnt(0)" ::: "memory");
    __syncthreads();
  }

  const int crow0 = bm*128 + wm*64;
  const int ccol0 = bn*128 + wn*64;
#pragma unroll
  for (int ni=0;ni<4;++ni){
    const int col = ccol0 + ni*16 + c16;
    const float bsum = bih[col] + bhh[col];
#pragma unroll
    for (int mi=0;mi<4;++mi){
      const int row = crow0 + mi*16 + rq*4;
#pragma unroll
      for (int r=0;r<4;++r)
        C[(size_t)(row+r)*GDIM + col] = acc[mi][ni][r] + bsum;
    }
  }
}

// ---------------- persistent recurrence over one chunk of timesteps ----------------
// 64 blocks x 512 threads. Block b owns hidden cols [16b,16b+16) -> 64 gate rows.
// Per step: stage full h (128KB, swizzled) from LLC into LDS once; 8 waves =
// (mh 0..1 batch-half) x (rh 0..1 row-half) x (kh 0..1 K-half) read fragments
// from LDS; one K-half partial reduction in LDS; 256-epilogue; swizzled h store
// write-through to LLC + monotone flags (R2-proven protocol).
__global__ __launch_bounds__(512,2) void lstm_rec(
    const unsigned short* __restrict__ whhb,   // bf16 [4096][1024]
    const float* __restrict__ xproj,           // fp32 [nsteps*64][4096]
    unsigned short* __restrict__ hbuf,         // bf16 [3][64*1024] ring (swizzled)
    float* __restrict__ cstate,                // fp32 [64*1024]
    float* __restrict__ outp,                  // fp32 d_out base
    unsigned int* __restrict__ bar,            // 64 flags, stride 32 uints
    int t0, int nsteps)
{
  const int tid = threadIdx.x;
  const int wv = tid >> 6, l = tid & 63;
  const int kh = wv & 1, rh = (wv >> 1) & 1, mh = wv >> 2;
  const int c16 = l & 15, rq = l >> 4;
  const int hc0 = blockIdx.x * 16;
  const int eb = tid >> 3, ej = tid & 7;      // epilogue (batch, col-pair base)

  __shared__ s16x8 hls4[8192];                          // 128 KB staged h
  __shared__ float part[64*66];                         // 16.9 KB partials
  __shared__ __align__(16) unsigned short hsh[64*16];   // 2 KB h bf16 staging

  // ---- W_hh slice -> registers: breg[nt][ks], gate row n = rh*32+nt*16+c16,
  //      whh row = (n&3)*HID + hc0 + (n>>2); k = kh*512 + ks*32 + rq*8
  s16x8 breg[2][16];
#pragma unroll
  for (int nt = 0; nt < 2; ++nt)
#pragma unroll
    for (int ks = 0; ks < 16; ++ks){
      const int n = rh*32 + nt*16 + c16;
      const int grow = (n & 3)*HID + hc0 + (n >> 2);
      const int k = kh*512 + ks*32 + rq*8;
      breg[nt][ks] = *(const s16x8*)(whhb + (size_t)grow*HID + k);
    }

  float creg0 = cstate[(size_t)eb*HID + hc0 + ej];
  float creg1 = cstate[(size_t)eb*HID + hc0 + ej + 8];
  float xpA[4], xpB[4];
#pragma unroll
  for (int g = 0; g < 4; ++g){
    xpA[g] = xproj[(size_t)eb*GDIM + g*HID + hc0 + ej];
    xpB[g] = xproj[(size_t)eb*GDIM + g*HID + hc0 + ej + 8];
  }

  int rb = t0 % 3;
  for (int t = t0; t < t0 + nsteps; ++t){
    int wb = rb + 1; if (wb == 3) wb = 0;

    // ---- stage h: 16 x 16B per thread, LLC-bypass loads -> LDS (linear mirror)
    {
      const char* hsrc = (const char*)(hbuf + (size_t)rb*65536) + tid*16;
      s16x8 tmp[16];
#define SL(I) asm volatile("global_load_dwordx4 %0, %1, off sc0 sc1" \
                           : "=v"(tmp[I]) : "v"(hsrc + (I)*8192))
      SL(0); SL(1); SL(2); SL(3); SL(4); SL(5); SL(6); SL(7);
      SL(8); SL(9); SL(10); SL(11); SL(12); SL(13); SL(14); SL(15);
#undef SL
      asm volatile("s_waitcnt vmcnt(0)" ::: "memory");
      __builtin_amdgcn_sched_barrier(0);
#pragma unroll
      for (int it = 0; it < 16; ++it)
        hls4[it*512 + tid] = tmp[it];
    }
    __syncthreads();

    // ---- MFMA: acc[msub][nt] over this wave's (batch-half, row-half, K-half)
    f32x4 acc[2][2];
#pragma unroll
    for (int ms = 0; ms < 2; ++ms)
#pragma unroll
      for (int nt = 0; nt < 2; ++nt) acc[ms][nt] = (f32x4){0.f,0.f,0.f,0.f};

#pragma unroll
    for (int ms = 0; ms < 2; ++ms){
      const int bl = mh*32 + ms*16 + c16;       // batch row in LDS
      const int bsw = bl & 7;
      s16x8 af[16];
#pragma unroll
      for (int ks = 0; ks < 16; ++ks)
        af[ks] = hls4[bl*128 + ((kh*64 + ks*4 + rq) ^ bsw)];
#pragma unroll
      for (int ks = 0; ks < 16; ++ks){
        acc[ms][0] = MFMA_BF16(af[ks], breg[0][ks], acc[ms][0]);
        acc[ms][1] = MFMA_BF16(af[ks], breg[1][ks], acc[ms][1]);
      }
    }

    // ---- K-half reduction through LDS: kh=0 writes, kh=1 adds
    if (kh == 0){
#pragma unroll
      for (int ms = 0; ms < 2; ++ms)
#pragma unroll
        for (int nt = 0; nt < 2; ++nt)
#pragma unroll
          for (int r = 0; r < 4; ++r)
            part[(mh*32 + ms*16 + rq*4 + r)*66 + rh*32 + nt*16 + c16] = acc[ms][nt][r];
    }
    __syncthreads();
    if (kh == 1){
#pragma unroll
      for (int ms = 0; ms < 2; ++ms)
#pragma unroll
        for (int nt = 0; nt < 2; ++nt)
#pragma unroll
          for (int r = 0; r < 4; ++r)
            part[(mh*32 + ms*16 + rq*4 + r)*66 + rh*32 + nt*16 + c16] += acc[ms][nt][r];
    }
    __syncthreads();

    // ---- epilogue: every thread handles (eb, ej) and (eb, ej+8)
    {
      const float vi0 = part[eb*66 + ej*4 + 0] + xpA[0];
      const float vf0 = part[eb*66 + ej*4 + 1] + xpA[1];
      const float vg0 = part[eb*66 + ej*4 + 2] + xpA[2];
      const float vo0 = part[eb*66 + ej*4 + 3] + xpA[3];
      const float vi1 = part[eb*66 + (ej+8)*4 + 0] + xpB[0];
      const float vf1 = part[eb*66 + (ej+8)*4 + 1] + xpB[1];
      const float vg1 = part[eb*66 + (ej+8)*4 + 2] + xpB[2];
      const float vo1 = part[eb*66 + (ej+8)*4 + 3] + xpB[3];

      const float i0 = 1.f/(1.f + __expf(-vi0)), f0 = 1.f/(1.f + __expf(-vf0));
      const float g0 = tanhf(vg0),               o0 = 1.f/(1.f + __expf(-vo0));
      const float i1 = 1.f/(1.f + __expf(-vi1)), f1 = 1.f/(1.f + __expf(-vf1));
      const float g1 = tanhf(vg1),               o1 = 1.f/(1.f + __expf(-vo1));
      creg0 = f0*creg0 + i0*g0;
      creg1 = f1*creg1 + i1*g1;
      const float h0 = o0 * tanhf(creg0);
      const float h1 = o1 * tanhf(creg1);

      const size_t oidx = (size_t)eb*HID + hc0 + ej;
      outp[(size_t)t*65536 + oidx]     = h0;
      outp[(size_t)t*65536 + oidx + 8] = h1;
      hsh[eb*16 + ej]     = f2bf(h0);
      hsh[eb*16 + ej + 8] = f2bf(h1);
      if (t == SEQ-1){
        outp[(size_t)SEQ*65536 + oidx]             = h0;
        outp[(size_t)SEQ*65536 + oidx + 8]         = h1;
        outp[(size_t)SEQ*65536 + 65536 + oidx]     = creg0;
        outp[(size_t)SEQ*65536 + 65536 + oidx + 8] = creg1;
      }
      // prefetch next step's xproj (overlaps store-drain + poll)
      if (t+1 < t0 + nsteps){
        const size_t xrow = (size_t)(t+1 - t0)*NBATCH + eb;
#pragma unroll
        for (int g = 0; g < 4; ++g){
          xpA[g] = xproj[xrow*GDIM + g*HID + hc0 + ej];
          xpB[g] = xproj[xrow*GDIM + g*HID + hc0 + ej + 8];
        }
      }
    }
    __syncthreads();                         // hsh visible

    // ---- swizzled h ring store: 128 threads x 16B, write-through to LLC
    if (tid < 128){
      const int b = tid >> 1, half = tid & 1;
      const int swz = (blockIdx.x*2 + half) ^ (b & 7);
      const unsigned short* hp = hbuf + (size_t)wb*65536 + (size_t)b*HID + swz*8;
      s16x8 hv = *(const s16x8*)&hsh[b*16 + half*8];
      asm volatile("global_store_dwordx4 %0, %1, off sc0 sc1"
                   :: "v"(hp), "v"(hv) : "memory");
      asm volatile("s_waitcnt vmcnt(0)" ::: "memory");  // drain (waves 0-1)
    }
    __syncthreads();
    if (tid == 0){
      unsigned int* fp = bar + (blockIdx.x << 5);
      unsigned int fv = (unsigned int)(t + 1);
      asm volatile("global_store_dword %0, %1, off sc0 sc1"
                   :: "v"(fp), "v"(fv) : "memory");
    }
    // ---- acquire: 64 threads poll 64 flags in parallel (LLC loads)
    if (tid < 64){
      const unsigned int* fq = bar + (tid << 5);
      unsigned int fv; int spins = 0;
      do {
        asm volatile("global_load_dword %0, %1, off sc0 sc1\n\ts_waitcnt vmcnt(0)"
                     : "=v"(fv) : "v"(fq) : "memory");
      } while (fv < (unsigned int)(t + 1) && ++spins < (1 << 17));
    }
    __syncthreads();

    rb = wb;
  }

  cstate[(size_t)eb*HID + hc0 + ej]     = creg0;
  cstate[(size_t)eb*HID + hc0 + ej + 8] = creg1;
}

// ---------------------------------------------------------------------------
extern "C" void kernel_launch(void* const* d_in, const int* in_sizes, int n_in,
                              void* d_out, int out_size, void* d_ws, size_t ws_size,
                              hipStream_t stream)
{
  const float* inp = (const float*)d_in[0];
  const float* wih = (const float*)d_in[1];
  const float* whh = (const float*)d_in[2];
  const float* bih = (const float*)d_in[3];
  const float* bhh = (const float*)d_in[4];
  const float* h0  = (const float*)d_in[5];
  const float* c0  = (const float*)d_in[6];
  float* outp = (float*)d_out;

  auto alignup = [](size_t x){ return (x + 255) & ~(size_t)255; };
  auto need = [&](size_t ch)->size_t{
    size_t s = 0;
    s += alignup(ch*64*4096*4);          // xproj chunk
    s += alignup(ch*64*1024*2);          // in_bf16 chunk
    s += alignup((size_t)4096*1024*2);   // wih_bf16
    s += alignup((size_t)4096*1024*2);   // whh_bf16
    s += alignup((size_t)3*64*1024*2);   // hbuf ring
    s += alignup((size_t)64*1024*4);     // cstate
    s += alignup((size_t)64*32*4);       // flags
    return s;
  };
  int CH = 512;
  while (CH > 2 && need(CH) > ws_size) CH >>= 1;

  char* w = (char*)d_ws;
  float*          xproj  = (float*)w;          w += alignup((size_t)CH*64*4096*4);
  unsigned short* in_bf  = (unsigned short*)w; w += alignup((size_t)CH*64*1024*2);
  unsigned short* wih_bf = (unsigned short*)w; w += alignup((size_t)4096*1024*2);
  unsigned short* whh_bf = (unsigned short*)w; w += alignup((size_t)4096*1024*2);
  unsigned short* hbuf   = (unsigned short*)w; w += alignup((size_t)3*64*1024*2);
  float*          cst    = (float*)w;          w += alignup((size_t)64*1024*4);
  unsigned int*   bar    = (unsigned int*)w;

  hipMemsetAsync(bar, 0, 64*32*4, stream);

  cvt_bf16<<<4096, 256, 0, stream>>>(wih, wih_bf, 4096*1024/4);
  cvt_bf16<<<4096, 256, 0, stream>>>(whh, whh_bf, 4096*1024/4);
  init_state<<<256, 256, 0, stream>>>(h0, c0, hbuf, cst);

  const int nch = SEQ / CH;
  for (int ci = 0; ci < nch; ++ci){
    const int t0 = ci * CH;
    const int n4 = CH*64*1024/4;
    cvt_bf16<<<(n4+255)/256, 256, 0, stream>>>(inp + (size_t)t0*65536, in_bf, n4);
    gemm_xproj<<<dim3((CH*64/128)*32), 256, 0, stream>>>(in_bf, wih_bf, bih, bhh,
                                                         xproj, CH*64);
    lstm_rec<<<dim3(64), dim3(512), 0, stream>>>(whh_bf, xproj, hbuf, cst, outp,
                                                 bar, t0, CH);
  }
}